// Round 10
// baseline (810.243 us; speedup 1.0000x reference)
//
#include <hip/hip_runtime.h>
#include <hip/hip_bf16.h>
#include <math.h>

#define SCALE_ 0.17677669529663687f

// rope table in f32 (rope feeds only fine/sliding branches, never sel)
__global__ __launch_bounds__(256) void d_rope(float* __restrict__ rope) {
  int i = blockIdx.x * 256 + threadIdx.x;  // 8192 = 512*16
  int t = i >> 4, j = i & 15;
  float inv = powf(10000.f, -(float)j / 16.f);
  float ang = (float)t * inv;
  rope[2 * i]     = cosf(ang);
  rope[2 * i + 1] = sinf(ang);
}

// pm: block per ball; stage pos in LDS coalesced, 3 threads do the EXACT
// sequential t-ascending sum (sel-sensitive upstream value).
__global__ __launch_bounds__(256) void k_pm(const float* __restrict__ pos,
                                            float* __restrict__ pm) {
  __shared__ float ps[1536];
  int ball = blockIdx.x;
  for (int i = threadIdx.x; i < 1536; i += 256) ps[i] = pos[(size_t)ball * 1536 + i];
  __syncthreads();
  if (threadIdx.x < 3) {
    int c = threadIdx.x;
    float s = 0.f;
    for (int t = 0; t < 512; ++t) s += ps[t * 3 + c];
    pm[ball * 3 + c] = s * (1.f / 512.f);
  }
}

// hn: 32 tokens per block, hx staged in LDS (computed ONCE, same expression as
// before), per-token EXACT sequential d-ascending ss sum (sel-sensitive).
__global__ __launch_bounds__(256) void k_hn(const float* __restrict__ x,
                                            const float* __restrict__ pos,
                                            const float* __restrict__ pm,
                                            const float* __restrict__ Wpe,
                                            const float* __restrict__ bpe,
                                            const float* __restrict__ rmsw,
                                            float* __restrict__ hn) {
  __shared__ float hx[32][257];
  __shared__ float rr[32][3];
  __shared__ float invs[32];
  int tb = blockIdx.x * 32;  // 256 blocks
  if (threadIdx.x < 96) {
    int tok = threadIdx.x / 3, c = threadIdx.x % 3;
    rr[tok][c] = pos[(size_t)(tb + tok) * 3 + c] - pm[((tb + tok) >> 9) * 3 + c];
  }
  __syncthreads();
  for (int i = threadIdx.x; i < 8192; i += 256) {
    int tok = i >> 8, d = i & 255;
    float h = x[(size_t)(tb + tok) * 256 + d] + rr[tok][0] * Wpe[d] + rr[tok][1] * Wpe[256 + d]
            + rr[tok][2] * Wpe[512 + d] + bpe[d];
    hx[tok][d] = h;
  }
  __syncthreads();
  if (threadIdx.x < 32) {
    int tok = threadIdx.x;
    float ss = 0.f;
    for (int d = 0; d < 256; ++d) { float h = hx[tok][d]; ss += h * h; }
    invs[tok] = 1.f / sqrtf(ss * (1.f / 256.f) + 1e-6f);
  }
  __syncthreads();
  for (int i = threadIdx.x; i < 8192; i += 256) {
    int tok = i >> 8, d = i & 255;
    hn[(size_t)(tb + tok) * 256 + d] = hx[tok][d] * invs[tok] * rmsw[d];
  }
}

// qkv = hn @ Wqkv, tiled 64x64 (padded As), scatter q/k/v head-major
__global__ __launch_bounds__(256) void k_qkv(const float* __restrict__ A,
                                             const float* __restrict__ B,
                                             float* __restrict__ qo,
                                             float* __restrict__ ko,
                                             float* __restrict__ vo) {
  __shared__ float As[32][65];
  __shared__ float Bs[32][64];
  const int m0 = blockIdx.x * 64;
  const int n0 = blockIdx.y * 64;
  const int tid = threadIdx.x;
  const int tx = tid & 15, ty = tid >> 4;
  float acc[4][4] = {};
  for (int k0 = 0; k0 < 256; k0 += 32) {
#pragma unroll
    for (int i = 0; i < 8; ++i) {
      int li = tid + i * 256;
      int r = li >> 5, c = li & 31;
      As[c][r] = A[(size_t)(m0 + r) * 256 + k0 + c];
    }
#pragma unroll
    for (int i = 0; i < 8; ++i) {
      int li = tid + i * 256;
      int r = li >> 6, c = li & 63;
      Bs[r][c] = B[(size_t)(k0 + r) * 768 + n0 + c];
    }
    __syncthreads();
#pragma unroll
    for (int kk = 0; kk < 32; ++kk) {
      float a[4], b[4];
#pragma unroll
      for (int i = 0; i < 4; ++i) a[i] = As[kk][ty * 4 + i];
#pragma unroll
      for (int j = 0; j < 4; ++j) b[j] = Bs[kk][tx * 4 + j];
#pragma unroll
      for (int i = 0; i < 4; ++i)
#pragma unroll
        for (int j = 0; j < 4; ++j) acc[i][j] += a[i] * b[j];
    }
    __syncthreads();
  }
#pragma unroll
  for (int i = 0; i < 4; ++i) {
    int row = m0 + ty * 4 + i;
    int nb = row >> 9, t = row & 511;
#pragma unroll
    for (int j = 0; j < 4; ++j) {
      int col = n0 + tx * 4 + j;
      int which = col >> 8, cj = col & 255;
      int h = cj >> 5, d = cj & 31;
      float* dst = which == 0 ? qo : which == 1 ? ko : vo;
      dst[((size_t)(nb * 8 + h) * 512 + t) * 32 + d] = acc[i][j];
    }
  }
}

// rotate: dst = rope(src), one thread per (nh, t, pair)
__global__ __launch_bounds__(256) void d_rot(const float* __restrict__ src,
                                             const float* __restrict__ rope,
                                             float* __restrict__ dst) {
  int gid = blockIdx.x * 256 + threadIdx.x;  // 1,048,576
  int p = gid & 15;
  int t = (gid >> 4) & 511;
  int nh = gid >> 13;
  float c = rope[(t * 16 + p) * 2], s = rope[(t * 16 + p) * 2 + 1];
  const float* sp = src + ((size_t)nh * 512 + t) * 32;
  float x1 = sp[2 * p], x2 = sp[2 * p + 1];
  float* dp = dst + ((size_t)nh * 512 + t) * 32;
  dp[2 * p]     = x1 * c - x2 * s;
  dp[2 * p + 1] = x1 * s + x2 * c;
}

// gates = sigmoid(hn @ Wg), one thread per (token, j)
__global__ __launch_bounds__(256) void d_gates(const float* __restrict__ hn,
                                               const float* __restrict__ Wg,
                                               float* __restrict__ gates) {
  int gid = blockIdx.x * 256 + threadIdx.x;  // 196608
  int tok = gid / 24, j = gid % 24;
  const float* hr = hn + (size_t)tok * 256;
  float s = 0.f;
  for (int d = 0; d < 256; ++d) s += hr[d] * Wg[d * 24 + j];
  gates[gid] = 1.f / (1.f + expf(-s));
}

// gMLP layer 1: 128x64 tile, 8x4 acc, float4 LDS reads. K ascending => bit-exact.
__global__ __launch_bounds__(256) void k_gmlp1(const float* __restrict__ kv,
                                               const float* __restrict__ posw,
                                               const float* __restrict__ w1,
                                               float* __restrict__ hb) {
  __shared__ __align__(16) float As[32][132];  // [k][m], 132*4B=528B row: 16B-aligned
  __shared__ __align__(16) float Bs[32][68];   // [k][n], 68*4B=272B row: 16B-aligned
  const int h = blockIdx.z;
  const int m0 = blockIdx.x * 128;
  const int n0 = blockIdx.y * 64;
  const int tid = threadIdx.x;
  const int tx = tid & 15, ty = tid >> 4;
  float acc[8][4] = {};
  for (int k0 = 0; k0 < 1024; k0 += 32) {
#pragma unroll
    for (int i = 0; i < 16; ++i) {
      int li = tid + i * 256;
      int r = li >> 5, c = li & 31;
      int row = m0 + r;
      float vv = 0.f;
      if (row < 496) {
        int nb = row / 31, bb = row % 31;
        vv = kv[((size_t)(nb * 8 + h) * 512 + bb * 16) * 32 + k0 + c] + posw[h * 1024 + k0 + c];
      }
      As[c][r] = vv;
    }
#pragma unroll
    for (int i = 0; i < 8; ++i) {
      int li = tid + i * 256;
      int r = li >> 6, c = li & 63;
      Bs[r][c] = w1[(size_t)h * 1048576 + (size_t)(k0 + r) * 1024 + n0 + c];
    }
    __syncthreads();
#pragma unroll
    for (int kk = 0; kk < 32; ++kk) {
      float4 a0 = *reinterpret_cast<const float4*>(&As[kk][ty * 8]);
      float4 a1 = *reinterpret_cast<const float4*>(&As[kk][ty * 8 + 4]);
      float4 b0 = *reinterpret_cast<const float4*>(&Bs[kk][tx * 4]);
      float a[8] = {a0.x, a0.y, a0.z, a0.w, a1.x, a1.y, a1.z, a1.w};
      float b[4] = {b0.x, b0.y, b0.z, b0.w};
#pragma unroll
      for (int i = 0; i < 8; ++i)
#pragma unroll
        for (int j = 0; j < 4; ++j) acc[i][j] += a[i] * b[j];
    }
    __syncthreads();
  }
#pragma unroll
  for (int i = 0; i < 8; ++i) {
    int row = m0 + ty * 8 + i;
    if (row < 496) {
      float4 o;
      o.x = fmaxf(acc[i][0], 0.f); o.y = fmaxf(acc[i][1], 0.f);
      o.z = fmaxf(acc[i][2], 0.f); o.w = fmaxf(acc[i][3], 0.f);
      *reinterpret_cast<float4*>(&hb[((size_t)h * 496 + row) * 1024 + n0 + tx * 4]) = o;
    }
  }
}

// gMLP out: one thread per output, exact sequential i order (sel-sensitive)
__global__ __launch_bounds__(256) void d_g2(const float* __restrict__ hh,
                                            const float* __restrict__ w2,
                                            float* __restrict__ outp) {
  int gid = blockIdx.x * 256 + threadIdx.x;  // 126976
  int o = gid & 31;
  int rem = gid >> 5;                  // h*496 + row
  int h = rem / 496, row = rem % 496;
  int nb = row / 31, bb = row % 31;
  const float* hr = hh + (size_t)rem * 1024;
  const float* w2p = w2 + (size_t)h * 32768 + o;
  float s = 0.f;
  for (int i = 0; i < 1024; ++i) s += hr[i] * w2p[(size_t)i * 32];
  outp[((size_t)(nb * 8 + h) * 31 + bb) * 32 + o] = s;
}

// compressed attention, one thread per (nh, t): obuf = g0*c_out, emits sel
// (UNCHANGED: sel-sensitive)
__global__ __launch_bounds__(256) void d_cattn(const float* __restrict__ q,
                                               const float* __restrict__ ck,
                                               const float* __restrict__ cv,
                                               const float* __restrict__ mem_ck,
                                               const float* __restrict__ mem_cv,
                                               const float* __restrict__ gates,
                                               float* __restrict__ obuf,
                                               int* __restrict__ sel) {
  int gid = blockIdx.x * 256 + threadIdx.x;  // 65536
  int nh = gid >> 9, t = gid & 511;
  int h = nh & 7, ball = nh >> 3;
  const float* qp = q + (size_t)gid * 32;
  float sc[32];
  float mx = -INFINITY;
#pragma unroll
  for (int j = 0; j < 32; ++j) {
    float s = -INFINITY;
    bool valid = (j == 0) || (t >= (j - 1) * 16 + 31);
    if (valid) {
      const float* kp = (j == 0) ? (mem_ck + h * 32)
                                 : (ck + ((size_t)nh * 31 + (j - 1)) * 32);
      s = 0.f;
      for (int d = 0; d < 32; ++d) s += qp[d] * kp[d];
      s *= SCALE_;
    }
    sc[j] = s;
    mx = fmaxf(mx, s);
  }
  float e[32];
  float den = 0.f;
#pragma unroll
  for (int j = 0; j < 32; ++j) { e[j] = expf(sc[j] - mx); den += e[j]; }
  float num[32];
#pragma unroll
  for (int d = 0; d < 32; ++d) num[d] = 0.f;
#pragma unroll
  for (int j = 0; j < 32; ++j) {
    const float* vp = (j == 0) ? (mem_cv + h * 32)
                               : (cv + ((size_t)nh * 31 + (j - 1)) * 32);
    float p = e[j];
    for (int d = 0; d < 32; ++d) num[d] += p * vp[d];
  }
  float inv = 1.f / den;
  float g0 = gates[(size_t)(ball * 512 + t) * 24 + h * 3];
  float* op = obuf + (size_t)(ball * 512 + t) * 256 + h * 32;
  for (int d = 0; d < 32; ++d) op[d] = num[d] * inv * g0;

  int s_idx = 0;
  if (t >= 32) {
    int fn = t >> 5;
    float best = -INFINITY;
    for (int f = 0; f < fn; ++f) {
      float im = 0.f;
#pragma unroll
      for (int j = 0; j < 31; ++j) {
        int a = j * 16, b2 = a + 32, fa = f * 32, fb = fa + 32;
        int lo = a > fa ? a : fa;
        int hi = b2 < fb ? b2 : fb;
        if (hi > lo) im += e[j + 1] * (float)(hi - lo) * (1.f / 32.f);
      }
      if (im > best) { best = im; s_idx = f; }
    }
  }
  sel[gid] = s_idx;
}

// fine attention: block per (f0,h,nb), LDS-staged own tile, 8 lanes/query.
// Not sel-feeding => softmax reorder is threshold-safe.
__global__ __launch_bounds__(256) void k_fattn(const float* __restrict__ rq,
                                               const float* __restrict__ rk,
                                               const float* __restrict__ v,
                                               const int* __restrict__ sel,
                                               const float* __restrict__ gates,
                                               float* __restrict__ obuf) {
  int f0 = blockIdx.x, h = blockIdx.y, nb = blockIdx.z;
  int nh = nb * 8 + h;
  __shared__ float rqs[32][33], rks[32][33], vs[32][33];
  for (int i = threadIdx.x; i < 1024; i += 256) {
    int r = i >> 5, d = i & 31;
    size_t base = ((size_t)nh * 512 + f0 * 32 + r) * 32 + d;
    rqs[r][d] = rq[base];
    rks[r][d] = rk[base];
    vs[r][d]  = v[base];
  }
  __syncthreads();
  int qi = threadIdx.x >> 3, l = threadIdx.x & 7;
  int t = f0 * 32 + qi;
  int sb = sel[(size_t)nh * 512 + t];
  bool hs = (t >= 32);
  float p[8];
  float mx = -INFINITY;
#pragma unroll
  for (int kk2 = 0; kk2 < 8; ++kk2) {
    int kk = l * 8 + kk2;
    float s = -INFINITY;
    if (kk < 32) {
      if (qi >= kk) {
        s = 0.f;
#pragma unroll
        for (int d = 0; d < 32; ++d) s += rqs[qi][d] * rks[kk][d];
        s *= SCALE_;
      }
    } else if (hs) {
      const float* kp = rk + ((size_t)nh * 512 + sb * 32 + (kk - 32)) * 32;
      s = 0.f;
#pragma unroll
      for (int d = 0; d < 32; ++d) s += rqs[qi][d] * kp[d];
      s *= SCALE_;
    }
    p[kk2] = s;
    mx = fmaxf(mx, s);
  }
#pragma unroll
  for (int off = 4; off; off >>= 1) mx = fmaxf(mx, __shfl_xor(mx, off, 8));
  float sum = 0.f;
#pragma unroll
  for (int kk2 = 0; kk2 < 8; ++kk2) { p[kk2] = expf(p[kk2] - mx); sum += p[kk2]; }
#pragma unroll
  for (int off = 4; off; off >>= 1) sum += __shfl_xor(sum, off, 8);
  float inv = 1.f / sum;
  float acc[32];
#pragma unroll
  for (int d = 0; d < 32; ++d) acc[d] = 0.f;
#pragma unroll
  for (int kk2 = 0; kk2 < 8; ++kk2) {
    int kk = l * 8 + kk2;
    float pw = p[kk2] * inv;
    if (kk < 32) {
#pragma unroll
      for (int d = 0; d < 32; ++d) acc[d] += pw * vs[kk][d];
    } else if (hs) {
      const float* vp = v + ((size_t)nh * 512 + sb * 32 + (kk - 32)) * 32;
#pragma unroll
      for (int d = 0; d < 32; ++d) acc[d] += pw * vp[d];
    }
  }
#pragma unroll
  for (int off = 4; off; off >>= 1) {
#pragma unroll
    for (int d = 0; d < 32; ++d) acc[d] += __shfl_xor(acc[d], off, 8);
  }
  float g1 = gates[(size_t)(nb * 512 + t) * 24 + h * 3 + 1];
  float* op = obuf + (size_t)(nb * 512 + t) * 256 + h * 32;
#pragma unroll
  for (int j = 0; j < 4; ++j) op[l * 4 + j] += acc[l * 4 + j] * g1;
}

// sliding-window attention: block per (b,h,nb), LDS-staged 64-key window.
__global__ __launch_bounds__(256) void k_swattn(const float* __restrict__ rq,
                                                const float* __restrict__ rk,
                                                const float* __restrict__ v,
                                                const float* __restrict__ gates,
                                                float* __restrict__ obuf) {
  int b = blockIdx.x, h = blockIdx.y, nb = blockIdx.z;
  int nh = nb * 8 + h;
  __shared__ float rqs[32][33], k2s[64][33], v2s[64][33];
  for (int i = threadIdx.x; i < 1024; i += 256) {
    int r = i >> 5, d = i & 31;
    rqs[r][d] = rq[((size_t)nh * 512 + b * 32 + r) * 32 + d];
  }
  for (int i = threadIdx.x; i < 2048; i += 256) {
    int r = i >> 5, d = i & 31;
    int tk = (b - 1) * 32 + r;
    float kk_ = 0.f, vv_ = 0.f;
    if (tk >= 0) {
      kk_ = rk[((size_t)nh * 512 + tk) * 32 + d];
      vv_ = v[((size_t)nh * 512 + tk) * 32 + d];
    }
    k2s[r][d] = kk_;
    v2s[r][d] = vv_;
  }
  __syncthreads();
  int qi = threadIdx.x >> 3, l = threadIdx.x & 7;
  int t = b * 32 + qi;
  float p[8];
  float mx = -INFINITY;
#pragma unroll
  for (int kk2 = 0; kk2 < 8; ++kk2) {
    int kk = l * 8 + kk2;
    bool valid = (kk > qi) && (kk <= qi + 32) && ((b > 0) || (kk >= 32));
    float s = -INFINITY;
    if (valid) {
      s = 0.f;
#pragma unroll
      for (int d = 0; d < 32; ++d) s += rqs[qi][d] * k2s[kk][d];
      s *= SCALE_;
    }
    p[kk2] = s;
    mx = fmaxf(mx, s);
  }
#pragma unroll
  for (int off = 4; off; off >>= 1) mx = fmaxf(mx, __shfl_xor(mx, off, 8));
  float sum = 0.f;
#pragma unroll
  for (int kk2 = 0; kk2 < 8; ++kk2) { p[kk2] = expf(p[kk2] - mx); sum += p[kk2]; }
#pragma unroll
  for (int off = 4; off; off >>= 1) sum += __shfl_xor(sum, off, 8);
  float inv = 1.f / sum;
  float acc[32];
#pragma unroll
  for (int d = 0; d < 32; ++d) acc[d] = 0.f;
#pragma unroll
  for (int kk2 = 0; kk2 < 8; ++kk2) {
    int kk = l * 8 + kk2;
    float pw = p[kk2] * inv;  // invalid entries have p=0
#pragma unroll
    for (int d = 0; d < 32; ++d) acc[d] += pw * v2s[kk][d];
  }
#pragma unroll
  for (int off = 4; off; off >>= 1) {
#pragma unroll
    for (int d = 0; d < 32; ++d) acc[d] += __shfl_xor(acc[d], off, 8);
  }
  float g2 = gates[(size_t)(nb * 512 + t) * 24 + h * 3 + 2];
  float* op = obuf + (size_t)(nb * 512 + t) * 256 + h * 32;
#pragma unroll
  for (int j = 0; j < 4; ++j) op[l * 4 + j] += acc[l * 4 + j] * g2;
}

// final projection tiled (padded As): out = obuf @ Wo (f32 store)
__global__ __launch_bounds__(256) void k_out(const float* __restrict__ A,
                                             const float* __restrict__ B,
                                             float* __restrict__ C) {
  __shared__ float As[32][65];
  __shared__ float Bs[32][64];
  const int m0 = blockIdx.x * 64;
  const int n0 = blockIdx.y * 64;
  const int tid = threadIdx.x;
  const int tx = tid & 15, ty = tid >> 4;
  float acc[4][4] = {};
  for (int k0 = 0; k0 < 256; k0 += 32) {
#pragma unroll
    for (int i = 0; i < 8; ++i) {
      int li = tid + i * 256;
      int r = li >> 5, c = li & 31;
      As[c][r] = A[(size_t)(m0 + r) * 256 + k0 + c];
    }
#pragma unroll
    for (int i = 0; i < 8; ++i) {
      int li = tid + i * 256;
      int r = li >> 6, c = li & 63;
      Bs[r][c] = B[(size_t)(k0 + r) * 256 + n0 + c];
    }
    __syncthreads();
#pragma unroll
    for (int kk = 0; kk < 32; ++kk) {
      float a[4], b[4];
#pragma unroll
      for (int i = 0; i < 4; ++i) a[i] = As[kk][ty * 4 + i];
#pragma unroll
      for (int j = 0; j < 4; ++j) b[j] = Bs[kk][tx * 4 + j];
#pragma unroll
      for (int i = 0; i < 4; ++i)
#pragma unroll
        for (int j = 0; j < 4; ++j) acc[i][j] += a[i] * b[j];
    }
    __syncthreads();
  }
#pragma unroll
  for (int i = 0; i < 4; ++i) {
    int row = m0 + ty * 4 + i;
#pragma unroll
    for (int j = 0; j < 4; ++j)
      C[(size_t)row * 256 + n0 + tx * 4 + j] = acc[i][j];
  }
}

extern "C" void kernel_launch(void* const* d_in, const int* in_sizes, int n_in,
                              void* d_out, int out_size, void* d_ws, size_t ws_size,
                              hipStream_t stream) {
  const float* x      = (const float*)d_in[0];
  const float* pos    = (const float*)d_in[1];
  const float* Wpe    = (const float*)d_in[2];
  const float* bpe    = (const float*)d_in[3];
  const float* rms_w  = (const float*)d_in[4];
  const float* Wqkv   = (const float*)d_in[5];
  const float* kpos   = (const float*)d_in[6];
  const float* vpos   = (const float*)d_in[7];
  const float* kw1    = (const float*)d_in[8];
  const float* kw2    = (const float*)d_in[9];
  const float* vw1    = (const float*)d_in[10];
  const float* vw2    = (const float*)d_in[11];
  const float* mem_ck = (const float*)d_in[12];
  const float* mem_cv = (const float*)d_in[13];
  const float* Wg     = (const float*)d_in[14];
  const float* Wo     = (const float*)d_in[15];
  float* out = (float*)d_out;

  float* ws = (float*)d_ws;
  const size_t TOK = 2097152;  // 8192*256
  float* hn    = ws;
  float* q     = ws + TOK;
  float* k     = ws + 2 * TOK;
  float* v     = ws + 3 * TOK;
  float* rq    = ws + 4 * TOK;
  float* rk    = ws + 5 * TOK;
  float* obuf  = ws + 6 * TOK;
  float* hh    = ws + 7 * TOK;       // 4,063,232
  float* ck    = hh + 4063232;
  float* cv    = ck + 126976;
  float* gates = cv + 126976;
  float* rope  = gates + 196608;
  float* pm    = rope + 16384;
  int*   sel   = (int*)(pm + 64);

  d_rope<<<32, 256, 0, stream>>>(rope);
  k_pm<<<16, 256, 0, stream>>>(pos, pm);
  k_hn<<<256, 256, 0, stream>>>(x, pos, pm, Wpe, bpe, rms_w, hn);
  k_qkv<<<dim3(128, 12), 256, 0, stream>>>(hn, Wqkv, q, k, v);
  d_rot<<<4096, 256, 0, stream>>>(q, rope, rq);
  d_rot<<<4096, 256, 0, stream>>>(k, rope, rk);
  d_gates<<<768, 256, 0, stream>>>(hn, Wg, gates);
  k_gmlp1<<<dim3(4, 16, 8), 256, 0, stream>>>(k, kpos, kw1, hh);
  d_g2<<<496, 256, 0, stream>>>(hh, kw2, ck);
  k_gmlp1<<<dim3(4, 16, 8), 256, 0, stream>>>(v, vpos, vw1, hh);
  d_g2<<<496, 256, 0, stream>>>(hh, vw2, cv);
  d_cattn<<<256, 256, 0, stream>>>(q, ck, cv, mem_ck, mem_cv, gates, obuf, sel);
  k_fattn<<<dim3(16, 8, 16), 256, 0, stream>>>(rq, rk, v, sel, gates, obuf);
  k_swattn<<<dim3(16, 8, 16), 256, 0, stream>>>(rq, rk, v, gates, obuf);
  k_out<<<dim3(128, 4), 256, 0, stream>>>(obuf, Wo, out);
}

// Round 11
// 670.599 us; speedup vs baseline: 1.2082x; 1.2082x over previous
//
#include <hip/hip_runtime.h>
#include <hip/hip_bf16.h>
#include <math.h>

#define SCALE_ 0.17677669529663687f

// rope table in f32 (rope feeds only fine/sliding branches, never sel)
__global__ __launch_bounds__(256) void d_rope(float* __restrict__ rope) {
  int i = blockIdx.x * 256 + threadIdx.x;  // 8192 = 512*16
  int t = i >> 4, j = i & 15;
  float inv = powf(10000.f, -(float)j / 16.f);
  float ang = (float)t * inv;
  rope[2 * i]     = cosf(ang);
  rope[2 * i + 1] = sinf(ang);
}

// pm: block per ball; stage pos in LDS coalesced, 3 threads do the EXACT
// sequential t-ascending sum (sel-sensitive upstream value).
__global__ __launch_bounds__(256) void k_pm(const float* __restrict__ pos,
                                            float* __restrict__ pm) {
  __shared__ float ps[1536];
  int ball = blockIdx.x;
  for (int i = threadIdx.x; i < 1536; i += 256) ps[i] = pos[(size_t)ball * 1536 + i];
  __syncthreads();
  if (threadIdx.x < 3) {
    int c = threadIdx.x;
    float s = 0.f;
    for (int t = 0; t < 512; ++t) s += ps[t * 3 + c];
    pm[ball * 3 + c] = s * (1.f / 512.f);
  }
}

// hn: 32 tokens per block, hx staged in LDS, per-token EXACT sequential ss sum.
__global__ __launch_bounds__(256) void k_hn(const float* __restrict__ x,
                                            const float* __restrict__ pos,
                                            const float* __restrict__ pm,
                                            const float* __restrict__ Wpe,
                                            const float* __restrict__ bpe,
                                            const float* __restrict__ rmsw,
                                            float* __restrict__ hn) {
  __shared__ float hx[32][257];
  __shared__ float rr[32][3];
  __shared__ float invs[32];
  int tb = blockIdx.x * 32;  // 256 blocks
  if (threadIdx.x < 96) {
    int tok = threadIdx.x / 3, c = threadIdx.x % 3;
    rr[tok][c] = pos[(size_t)(tb + tok) * 3 + c] - pm[((tb + tok) >> 9) * 3 + c];
  }
  __syncthreads();
  for (int i = threadIdx.x; i < 8192; i += 256) {
    int tok = i >> 8, d = i & 255;
    float h = x[(size_t)(tb + tok) * 256 + d] + rr[tok][0] * Wpe[d] + rr[tok][1] * Wpe[256 + d]
            + rr[tok][2] * Wpe[512 + d] + bpe[d];
    hx[tok][d] = h;
  }
  __syncthreads();
  if (threadIdx.x < 32) {
    int tok = threadIdx.x;
    float ss = 0.f;
    for (int d = 0; d < 256; ++d) { float h = hx[tok][d]; ss += h * h; }
    invs[tok] = 1.f / sqrtf(ss * (1.f / 256.f) + 1e-6f);
  }
  __syncthreads();
  for (int i = threadIdx.x; i < 8192; i += 256) {
    int tok = i >> 8, d = i & 255;
    hn[(size_t)(tb + tok) * 256 + d] = hx[tok][d] * invs[tok] * rmsw[d];
  }
}

// qkv = hn @ Wqkv, tiled 64x64. A untransposed [m][k] (conflict-free writes,
// broadcast reads); B padded for float4 reads. K ascending => bit-exact.
__global__ __launch_bounds__(256) void k_qkv(const float* __restrict__ A,
                                             const float* __restrict__ B,
                                             float* __restrict__ qo,
                                             float* __restrict__ ko,
                                             float* __restrict__ vo) {
  __shared__ float As[64][33];
  __shared__ __align__(16) float Bs[32][68];
  const int m0 = blockIdx.x * 64;
  const int n0 = blockIdx.y * 64;
  const int tid = threadIdx.x;
  const int tx = tid & 15, ty = tid >> 4;
  float acc[4][4] = {};
  for (int k0 = 0; k0 < 256; k0 += 32) {
#pragma unroll
    for (int i = 0; i < 8; ++i) {
      int li = tid + i * 256;
      int m = li >> 5, c = li & 31;
      As[m][c] = A[(size_t)(m0 + m) * 256 + k0 + c];
    }
#pragma unroll
    for (int i = 0; i < 8; ++i) {
      int li = tid + i * 256;
      int r = li >> 6, c = li & 63;
      Bs[r][c] = B[(size_t)(k0 + r) * 768 + n0 + c];
    }
    __syncthreads();
#pragma unroll
    for (int kk = 0; kk < 32; ++kk) {
      float a[4];
#pragma unroll
      for (int i = 0; i < 4; ++i) a[i] = As[ty * 4 + i][kk];
      float4 b4 = *reinterpret_cast<const float4*>(&Bs[kk][tx * 4]);
      float b[4] = {b4.x, b4.y, b4.z, b4.w};
#pragma unroll
      for (int i = 0; i < 4; ++i)
#pragma unroll
        for (int j = 0; j < 4; ++j) acc[i][j] += a[i] * b[j];
    }
    __syncthreads();
  }
#pragma unroll
  for (int i = 0; i < 4; ++i) {
    int row = m0 + ty * 4 + i;
    int nb = row >> 9, t = row & 511;
#pragma unroll
    for (int j = 0; j < 4; ++j) {
      int col = n0 + tx * 4 + j;
      int which = col >> 8, cj = col & 255;
      int h = cj >> 5, d = cj & 31;
      float* dst = which == 0 ? qo : which == 1 ? ko : vo;
      dst[((size_t)(nb * 8 + h) * 512 + t) * 32 + d] = acc[i][j];
    }
  }
}

// rotate: dst = rope(src), one thread per (nh, t, pair)
__global__ __launch_bounds__(256) void d_rot(const float* __restrict__ src,
                                             const float* __restrict__ rope,
                                             float* __restrict__ dst) {
  int gid = blockIdx.x * 256 + threadIdx.x;  // 1,048,576
  int p = gid & 15;
  int t = (gid >> 4) & 511;
  int nh = gid >> 13;
  float c = rope[(t * 16 + p) * 2], s = rope[(t * 16 + p) * 2 + 1];
  const float* sp = src + ((size_t)nh * 512 + t) * 32;
  float x1 = sp[2 * p], x2 = sp[2 * p + 1];
  float* dp = dst + ((size_t)nh * 512 + t) * 32;
  dp[2 * p]     = x1 * c - x2 * s;
  dp[2 * p + 1] = x1 * s + x2 * c;
}

// gates = sigmoid(hn @ Wg), one thread per (token, j)
__global__ __launch_bounds__(256) void d_gates(const float* __restrict__ hn,
                                               const float* __restrict__ Wg,
                                               float* __restrict__ gates) {
  int gid = blockIdx.x * 256 + threadIdx.x;  // 196608
  int tok = gid / 24, j = gid % 24;
  const float* hr = hn + (size_t)tok * 256;
  float s = 0.f;
  for (int d = 0; d < 256; ++d) s += hr[d] * Wg[d * 24 + j];
  gates[gid] = 1.f / (1.f + expf(-s));
}

// gMLP layer 1: 64x64 tile, A untransposed, B float4. K ascending => bit-exact.
__global__ __launch_bounds__(256) void k_gmlp1(const float* __restrict__ kv,
                                               const float* __restrict__ posw,
                                               const float* __restrict__ w1,
                                               float* __restrict__ hb) {
  __shared__ float As[64][33];
  __shared__ __align__(16) float Bs[32][68];
  const int h = blockIdx.z;
  const int m0 = blockIdx.x * 64;
  const int n0 = blockIdx.y * 64;
  const int tid = threadIdx.x;
  const int tx = tid & 15, ty = tid >> 4;
  float acc[4][4] = {};
  for (int k0 = 0; k0 < 1024; k0 += 32) {
#pragma unroll
    for (int i = 0; i < 8; ++i) {
      int li = tid + i * 256;
      int m = li >> 5, c = li & 31;
      int row = m0 + m;
      float vv = 0.f;
      if (row < 496) {
        int nb = row / 31, bb = row % 31;
        vv = kv[((size_t)(nb * 8 + h) * 512 + bb * 16) * 32 + k0 + c] + posw[h * 1024 + k0 + c];
      }
      As[m][c] = vv;
    }
#pragma unroll
    for (int i = 0; i < 8; ++i) {
      int li = tid + i * 256;
      int r = li >> 6, c = li & 63;
      Bs[r][c] = w1[(size_t)h * 1048576 + (size_t)(k0 + r) * 1024 + n0 + c];
    }
    __syncthreads();
#pragma unroll
    for (int kk = 0; kk < 32; ++kk) {
      float a[4];
#pragma unroll
      for (int i = 0; i < 4; ++i) a[i] = As[ty * 4 + i][kk];
      float4 b4 = *reinterpret_cast<const float4*>(&Bs[kk][tx * 4]);
      float b[4] = {b4.x, b4.y, b4.z, b4.w};
#pragma unroll
      for (int i = 0; i < 4; ++i)
#pragma unroll
        for (int j = 0; j < 4; ++j) acc[i][j] += a[i] * b[j];
    }
    __syncthreads();
  }
#pragma unroll
  for (int i = 0; i < 4; ++i) {
    int row = m0 + ty * 4 + i;
    if (row < 496) {
#pragma unroll
      for (int j = 0; j < 4; ++j)
        hb[((size_t)h * 496 + row) * 1024 + n0 + tx * 4 + j] = fmaxf(acc[i][j], 0.f);
    }
  }
}

// gMLP out: one thread per output, exact sequential i order (sel-sensitive)
__global__ __launch_bounds__(256) void d_g2(const float* __restrict__ hh,
                                            const float* __restrict__ w2,
                                            float* __restrict__ outp) {
  int gid = blockIdx.x * 256 + threadIdx.x;  // 126976
  int o = gid & 31;
  int rem = gid >> 5;                  // h*496 + row
  int h = rem / 496, row = rem % 496;
  int nb = row / 31, bb = row % 31;
  const float* hr = hh + (size_t)rem * 1024;
  const float* w2p = w2 + (size_t)h * 32768 + o;
  float s = 0.f;
  for (int i = 0; i < 1024; ++i) s += hr[i] * w2p[(size_t)i * 32];
  outp[((size_t)(nb * 8 + h) * 31 + bb) * 32 + o] = s;
}

// compressed attention, one thread per (nh, t): obuf = g0*c_out, emits sel
// (UNCHANGED: sel-sensitive)
__global__ __launch_bounds__(256) void d_cattn(const float* __restrict__ q,
                                               const float* __restrict__ ck,
                                               const float* __restrict__ cv,
                                               const float* __restrict__ mem_ck,
                                               const float* __restrict__ mem_cv,
                                               const float* __restrict__ gates,
                                               float* __restrict__ obuf,
                                               int* __restrict__ sel) {
  int gid = blockIdx.x * 256 + threadIdx.x;  // 65536
  int nh = gid >> 9, t = gid & 511;
  int h = nh & 7, ball = nh >> 3;
  const float* qp = q + (size_t)gid * 32;
  float sc[32];
  float mx = -INFINITY;
#pragma unroll
  for (int j = 0; j < 32; ++j) {
    float s = -INFINITY;
    bool valid = (j == 0) || (t >= (j - 1) * 16 + 31);
    if (valid) {
      const float* kp = (j == 0) ? (mem_ck + h * 32)
                                 : (ck + ((size_t)nh * 31 + (j - 1)) * 32);
      s = 0.f;
      for (int d = 0; d < 32; ++d) s += qp[d] * kp[d];
      s *= SCALE_;
    }
    sc[j] = s;
    mx = fmaxf(mx, s);
  }
  float e[32];
  float den = 0.f;
#pragma unroll
  for (int j = 0; j < 32; ++j) { e[j] = expf(sc[j] - mx); den += e[j]; }
  float num[32];
#pragma unroll
  for (int d = 0; d < 32; ++d) num[d] = 0.f;
#pragma unroll
  for (int j = 0; j < 32; ++j) {
    const float* vp = (j == 0) ? (mem_cv + h * 32)
                               : (cv + ((size_t)nh * 31 + (j - 1)) * 32);
    float p = e[j];
    for (int d = 0; d < 32; ++d) num[d] += p * vp[d];
  }
  float inv = 1.f / den;
  float g0 = gates[(size_t)(ball * 512 + t) * 24 + h * 3];
  float* op = obuf + (size_t)(ball * 512 + t) * 256 + h * 32;
  for (int d = 0; d < 32; ++d) op[d] = num[d] * inv * g0;

  int s_idx = 0;
  if (t >= 32) {
    int fn = t >> 5;
    float best = -INFINITY;
    for (int f = 0; f < fn; ++f) {
      float im = 0.f;
#pragma unroll
      for (int j = 0; j < 31; ++j) {
        int a = j * 16, b2 = a + 32, fa = f * 32, fb = fa + 32;
        int lo = a > fa ? a : fa;
        int hi = b2 < fb ? b2 : fb;
        if (hi > lo) im += e[j + 1] * (float)(hi - lo) * (1.f / 32.f);
      }
      if (im > best) { best = im; s_idx = f; }
    }
  }
  sel[gid] = s_idx;
}

// fine attention: block per (f0,h,nb), LDS-staged own tile, 8 lanes/query.
__global__ __launch_bounds__(256) void k_fattn(const float* __restrict__ rq,
                                               const float* __restrict__ rk,
                                               const float* __restrict__ v,
                                               const int* __restrict__ sel,
                                               const float* __restrict__ gates,
                                               float* __restrict__ obuf) {
  int f0 = blockIdx.x, h = blockIdx.y, nb = blockIdx.z;
  int nh = nb * 8 + h;
  __shared__ float rqs[32][33], rks[32][33], vs[32][33];
  for (int i = threadIdx.x; i < 1024; i += 256) {
    int r = i >> 5, d = i & 31;
    size_t base = ((size_t)nh * 512 + f0 * 32 + r) * 32 + d;
    rqs[r][d] = rq[base];
    rks[r][d] = rk[base];
    vs[r][d]  = v[base];
  }
  __syncthreads();
  int qi = threadIdx.x >> 3, l = threadIdx.x & 7;
  int t = f0 * 32 + qi;
  int sb = sel[(size_t)nh * 512 + t];
  bool hs = (t >= 32);
  float p[8];
  float mx = -INFINITY;
#pragma unroll
  for (int kk2 = 0; kk2 < 8; ++kk2) {
    int kk = l * 8 + kk2;
    float s = -INFINITY;
    if (kk < 32) {
      if (qi >= kk) {
        s = 0.f;
#pragma unroll
        for (int d = 0; d < 32; ++d) s += rqs[qi][d] * rks[kk][d];
        s *= SCALE_;
      }
    } else if (hs) {
      const float* kp = rk + ((size_t)nh * 512 + sb * 32 + (kk - 32)) * 32;
      s = 0.f;
#pragma unroll
      for (int d = 0; d < 32; ++d) s += rqs[qi][d] * kp[d];
      s *= SCALE_;
    }
    p[kk2] = s;
    mx = fmaxf(mx, s);
  }
#pragma unroll
  for (int off = 4; off; off >>= 1) mx = fmaxf(mx, __shfl_xor(mx, off, 8));
  float sum = 0.f;
#pragma unroll
  for (int kk2 = 0; kk2 < 8; ++kk2) { p[kk2] = expf(p[kk2] - mx); sum += p[kk2]; }
#pragma unroll
  for (int off = 4; off; off >>= 1) sum += __shfl_xor(sum, off, 8);
  float inv = 1.f / sum;
  float acc[32];
#pragma unroll
  for (int d = 0; d < 32; ++d) acc[d] = 0.f;
#pragma unroll
  for (int kk2 = 0; kk2 < 8; ++kk2) {
    int kk = l * 8 + kk2;
    float pw = p[kk2] * inv;
    if (kk < 32) {
#pragma unroll
      for (int d = 0; d < 32; ++d) acc[d] += pw * vs[kk][d];
    } else if (hs) {
      const float* vp = v + ((size_t)nh * 512 + sb * 32 + (kk - 32)) * 32;
#pragma unroll
      for (int d = 0; d < 32; ++d) acc[d] += pw * vp[d];
    }
  }
#pragma unroll
  for (int off = 4; off; off >>= 1) {
#pragma unroll
    for (int d = 0; d < 32; ++d) acc[d] += __shfl_xor(acc[d], off, 8);
  }
  float g1 = gates[(size_t)(nb * 512 + t) * 24 + h * 3 + 1];
  float* op = obuf + (size_t)(nb * 512 + t) * 256 + h * 32;
#pragma unroll
  for (int j = 0; j < 4; ++j) op[l * 4 + j] += acc[l * 4 + j] * g1;
}

// sliding-window attention: block per (b,h,nb), LDS-staged 64-key window.
__global__ __launch_bounds__(256) void k_swattn(const float* __restrict__ rq,
                                                const float* __restrict__ rk,
                                                const float* __restrict__ v,
                                                const float* __restrict__ gates,
                                                float* __restrict__ obuf) {
  int b = blockIdx.x, h = blockIdx.y, nb = blockIdx.z;
  int nh = nb * 8 + h;
  __shared__ float rqs[32][33], k2s[64][33], v2s[64][33];
  for (int i = threadIdx.x; i < 1024; i += 256) {
    int r = i >> 5, d = i & 31;
    rqs[r][d] = rq[((size_t)nh * 512 + b * 32 + r) * 32 + d];
  }
  for (int i = threadIdx.x; i < 2048; i += 256) {
    int r = i >> 5, d = i & 31;
    int tk = (b - 1) * 32 + r;
    float kk_ = 0.f, vv_ = 0.f;
    if (tk >= 0) {
      kk_ = rk[((size_t)nh * 512 + tk) * 32 + d];
      vv_ = v[((size_t)nh * 512 + tk) * 32 + d];
    }
    k2s[r][d] = kk_;
    v2s[r][d] = vv_;
  }
  __syncthreads();
  int qi = threadIdx.x >> 3, l = threadIdx.x & 7;
  int t = b * 32 + qi;
  float p[8];
  float mx = -INFINITY;
#pragma unroll
  for (int kk2 = 0; kk2 < 8; ++kk2) {
    int kk = l * 8 + kk2;
    bool valid = (kk > qi) && (kk <= qi + 32) && ((b > 0) || (kk >= 32));
    float s = -INFINITY;
    if (valid) {
      s = 0.f;
#pragma unroll
      for (int d = 0; d < 32; ++d) s += rqs[qi][d] * k2s[kk][d];
      s *= SCALE_;
    }
    p[kk2] = s;
    mx = fmaxf(mx, s);
  }
#pragma unroll
  for (int off = 4; off; off >>= 1) mx = fmaxf(mx, __shfl_xor(mx, off, 8));
  float sum = 0.f;
#pragma unroll
  for (int kk2 = 0; kk2 < 8; ++kk2) { p[kk2] = expf(p[kk2] - mx); sum += p[kk2]; }
#pragma unroll
  for (int off = 4; off; off >>= 1) sum += __shfl_xor(sum, off, 8);
  float inv = 1.f / sum;
  float acc[32];
#pragma unroll
  for (int d = 0; d < 32; ++d) acc[d] = 0.f;
#pragma unroll
  for (int kk2 = 0; kk2 < 8; ++kk2) {
    int kk = l * 8 + kk2;
    float pw = p[kk2] * inv;  // invalid entries have p=0
#pragma unroll
    for (int d = 0; d < 32; ++d) acc[d] += pw * v2s[kk][d];
  }
#pragma unroll
  for (int off = 4; off; off >>= 1) {
#pragma unroll
    for (int d = 0; d < 32; ++d) acc[d] += __shfl_xor(acc[d], off, 8);
  }
  float g2 = gates[(size_t)(nb * 512 + t) * 24 + h * 3 + 2];
  float* op = obuf + (size_t)(nb * 512 + t) * 256 + h * 32;
#pragma unroll
  for (int j = 0; j < 4; ++j) op[l * 4 + j] += acc[l * 4 + j] * g2;
}

// final projection tiled: out = obuf @ Wo (f32 store); same A/B scheme
__global__ __launch_bounds__(256) void k_out(const float* __restrict__ A,
                                             const float* __restrict__ B,
                                             float* __restrict__ C) {
  __shared__ float As[64][33];
  __shared__ __align__(16) float Bs[32][68];
  const int m0 = blockIdx.x * 64;
  const int n0 = blockIdx.y * 64;
  const int tid = threadIdx.x;
  const int tx = tid & 15, ty = tid >> 4;
  float acc[4][4] = {};
  for (int k0 = 0; k0 < 256; k0 += 32) {
#pragma unroll
    for (int i = 0; i < 8; ++i) {
      int li = tid + i * 256;
      int m = li >> 5, c = li & 31;
      As[m][c] = A[(size_t)(m0 + m) * 256 + k0 + c];
    }
#pragma unroll
    for (int i = 0; i < 8; ++i) {
      int li = tid + i * 256;
      int r = li >> 6, c = li & 63;
      Bs[r][c] = B[(size_t)(k0 + r) * 256 + n0 + c];
    }
    __syncthreads();
#pragma unroll
    for (int kk = 0; kk < 32; ++kk) {
      float a[4];
#pragma unroll
      for (int i = 0; i < 4; ++i) a[i] = As[ty * 4 + i][kk];
      float4 b4 = *reinterpret_cast<const float4*>(&Bs[kk][tx * 4]);
      float b[4] = {b4.x, b4.y, b4.z, b4.w};
#pragma unroll
      for (int i = 0; i < 4; ++i)
#pragma unroll
        for (int j = 0; j < 4; ++j) acc[i][j] += a[i] * b[j];
    }
    __syncthreads();
  }
#pragma unroll
  for (int i = 0; i < 4; ++i) {
    int row = m0 + ty * 4 + i;
#pragma unroll
    for (int j = 0; j < 4; ++j)
      C[(size_t)row * 256 + n0 + tx * 4 + j] = acc[i][j];
  }
}

extern "C" void kernel_launch(void* const* d_in, const int* in_sizes, int n_in,
                              void* d_out, int out_size, void* d_ws, size_t ws_size,
                              hipStream_t stream) {
  const float* x      = (const float*)d_in[0];
  const float* pos    = (const float*)d_in[1];
  const float* Wpe    = (const float*)d_in[2];
  const float* bpe    = (const float*)d_in[3];
  const float* rms_w  = (const float*)d_in[4];
  const float* Wqkv   = (const float*)d_in[5];
  const float* kpos   = (const float*)d_in[6];
  const float* vpos   = (const float*)d_in[7];
  const float* kw1    = (const float*)d_in[8];
  const float* kw2    = (const float*)d_in[9];
  const float* vw1    = (const float*)d_in[10];
  const float* vw2    = (const float*)d_in[11];
  const float* mem_ck = (const float*)d_in[12];
  const float* mem_cv = (const float*)d_in[13];
  const float* Wg     = (const float*)d_in[14];
  const float* Wo     = (const float*)d_in[15];
  float* out = (float*)d_out;

  float* ws = (float*)d_ws;
  const size_t TOK = 2097152;  // 8192*256
  float* hn    = ws;
  float* q     = ws + TOK;
  float* k     = ws + 2 * TOK;
  float* v     = ws + 3 * TOK;
  float* rq    = ws + 4 * TOK;
  float* rk    = ws + 5 * TOK;
  float* obuf  = ws + 6 * TOK;
  float* hh    = ws + 7 * TOK;       // 4,063,232
  float* ck    = hh + 4063232;
  float* cv    = ck + 126976;
  float* gates = cv + 126976;
  float* rope  = gates + 196608;
  float* pm    = rope + 16384;
  int*   sel   = (int*)(pm + 64);

  d_rope<<<32, 256, 0, stream>>>(rope);
  k_pm<<<16, 256, 0, stream>>>(pos, pm);
  k_hn<<<256, 256, 0, stream>>>(x, pos, pm, Wpe, bpe, rms_w, hn);
  k_qkv<<<dim3(128, 12), 256, 0, stream>>>(hn, Wqkv, q, k, v);
  d_rot<<<4096, 256, 0, stream>>>(q, rope, rq);
  d_rot<<<4096, 256, 0, stream>>>(k, rope, rk);
  d_gates<<<768, 256, 0, stream>>>(hn, Wg, gates);
  k_gmlp1<<<dim3(8, 16, 8), 256, 0, stream>>>(k, kpos, kw1, hh);
  d_g2<<<496, 256, 0, stream>>>(hh, kw2, ck);
  k_gmlp1<<<dim3(8, 16, 8), 256, 0, stream>>>(v, vpos, vw1, hh);
  d_g2<<<496, 256, 0, stream>>>(hh, vw2, cv);
  d_cattn<<<256, 256, 0, stream>>>(q, ck, cv, mem_ck, mem_cv, gates, obuf, sel);
  k_fattn<<<dim3(16, 8, 16), 256, 0, stream>>>(rq, rk, v, sel, gates, obuf);
  k_swattn<<<dim3(16, 8, 16), 256, 0, stream>>>(rq, rk, v, gates, obuf);
  k_out<<<dim3(128, 4), 256, 0, stream>>>(obuf, Wo, out);
}

// Round 12
// 611.693 us; speedup vs baseline: 1.3246x; 1.0963x over previous
//
#include <hip/hip_runtime.h>
#include <hip/hip_bf16.h>
#include <math.h>

#define SCALE_ 0.17677669529663687f

// rope table in f32 (rope feeds only fine/sliding branches, never sel)
__global__ __launch_bounds__(256) void d_rope(float* __restrict__ rope) {
  int i = blockIdx.x * 256 + threadIdx.x;  // 8192 = 512*16
  int t = i >> 4, j = i & 15;
  float inv = powf(10000.f, -(float)j / 16.f);
  float ang = (float)t * inv;
  rope[2 * i]     = cosf(ang);
  rope[2 * i + 1] = sinf(ang);
}

// pm: block per ball; EXACT sequential t-ascending sum (sel-sensitive).
__global__ __launch_bounds__(256) void k_pm(const float* __restrict__ pos,
                                            float* __restrict__ pm) {
  __shared__ float ps[1536];
  int ball = blockIdx.x;
  for (int i = threadIdx.x; i < 1536; i += 256) ps[i] = pos[(size_t)ball * 1536 + i];
  __syncthreads();
  if (threadIdx.x < 3) {
    int c = threadIdx.x;
    float s = 0.f;
    for (int t = 0; t < 512; ++t) s += ps[t * 3 + c];
    pm[ball * 3 + c] = s * (1.f / 512.f);
  }
}

// hn: 32 tokens per block, hx staged in LDS, per-token EXACT sequential ss sum.
__global__ __launch_bounds__(256) void k_hn(const float* __restrict__ x,
                                            const float* __restrict__ pos,
                                            const float* __restrict__ pm,
                                            const float* __restrict__ Wpe,
                                            const float* __restrict__ bpe,
                                            const float* __restrict__ rmsw,
                                            float* __restrict__ hn) {
  __shared__ float hx[32][257];
  __shared__ float rr[32][3];
  __shared__ float invs[32];
  int tb = blockIdx.x * 32;  // 256 blocks
  if (threadIdx.x < 96) {
    int tok = threadIdx.x / 3, c = threadIdx.x % 3;
    rr[tok][c] = pos[(size_t)(tb + tok) * 3 + c] - pm[((tb + tok) >> 9) * 3 + c];
  }
  __syncthreads();
  for (int i = threadIdx.x; i < 8192; i += 256) {
    int tok = i >> 8, d = i & 255;
    float h = x[(size_t)(tb + tok) * 256 + d] + rr[tok][0] * Wpe[d] + rr[tok][1] * Wpe[256 + d]
            + rr[tok][2] * Wpe[512 + d] + bpe[d];
    hx[tok][d] = h;
  }
  __syncthreads();
  if (threadIdx.x < 32) {
    int tok = threadIdx.x;
    float ss = 0.f;
    for (int d = 0; d < 256; ++d) { float h = hx[tok][d]; ss += h * h; }
    invs[tok] = 1.f / sqrtf(ss * (1.f / 256.f) + 1e-6f);
  }
  __syncthreads();
  for (int i = threadIdx.x; i < 8192; i += 256) {
    int tok = i >> 8, d = i & 255;
    hn[(size_t)(tb + tok) * 256 + d] = hx[tok][d] * invs[tok] * rmsw[d];
  }
}

// qkv = hn @ Wqkv, tiled 64x64, transposed As (2-way free), fused RoPE epilogue.
// Writes q,k,v AND rq,rk in one pass. K ascending => bit-exact.
__global__ __launch_bounds__(256) void k_qkv(const float* __restrict__ A,
                                             const float* __restrict__ B,
                                             const float* __restrict__ rope,
                                             float* __restrict__ qo,
                                             float* __restrict__ ko,
                                             float* __restrict__ vo,
                                             float* __restrict__ rqo,
                                             float* __restrict__ rko) {
  __shared__ float As[32][66];
  __shared__ __align__(16) float Bs[32][68];
  const int m0 = blockIdx.x * 64;
  const int n0 = blockIdx.y * 64;
  const int tid = threadIdx.x;
  const int tx = tid & 15, ty = tid >> 4;
  float acc[4][4] = {};
  for (int k0 = 0; k0 < 256; k0 += 32) {
#pragma unroll
    for (int i = 0; i < 8; ++i) {
      int li = tid + i * 256;
      int mm = li >> 5, c = li & 31;
      As[c][mm] = A[(size_t)(m0 + mm) * 256 + k0 + c];
    }
#pragma unroll
    for (int i = 0; i < 8; ++i) {
      int li = tid + i * 256;
      int r = li >> 6, c = li & 63;
      Bs[r][c] = B[(size_t)(k0 + r) * 768 + n0 + c];
    }
    __syncthreads();
#pragma unroll
    for (int kk = 0; kk < 32; ++kk) {
      float2 a0 = *reinterpret_cast<const float2*>(&As[kk][ty * 4]);
      float2 a1 = *reinterpret_cast<const float2*>(&As[kk][ty * 4 + 2]);
      float4 b4 = *reinterpret_cast<const float4*>(&Bs[kk][tx * 4]);
      float a[4] = {a0.x, a0.y, a1.x, a1.y};
      float b[4] = {b4.x, b4.y, b4.z, b4.w};
#pragma unroll
      for (int i = 0; i < 4; ++i)
#pragma unroll
        for (int j = 0; j < 4; ++j) acc[i][j] += a[i] * b[j];
    }
    __syncthreads();
  }
#pragma unroll
  for (int i = 0; i < 4; ++i) {
    int row = m0 + ty * 4 + i;
    int nb = row >> 9, t = row & 511;
#pragma unroll
    for (int j = 0; j < 4; j += 2) {
      int col = n0 + tx * 4 + j;
      int which = col >> 8, cj = col & 255;
      int h = cj >> 5, d = cj & 31;   // d is even; pair (d, d+1)
      float v1 = acc[i][j], v2 = acc[i][j + 1];
      size_t base = ((size_t)(nb * 8 + h) * 512 + t) * 32 + d;
      if (which == 0) {
        qo[base] = v1; qo[base + 1] = v2;
        int p = d >> 1;
        float cc = rope[(t * 16 + p) * 2], ss = rope[(t * 16 + p) * 2 + 1];
        rqo[base] = v1 * cc - v2 * ss; rqo[base + 1] = v1 * ss + v2 * cc;
      } else if (which == 1) {
        ko[base] = v1; ko[base + 1] = v2;
        int p = d >> 1;
        float cc = rope[(t * 16 + p) * 2], ss = rope[(t * 16 + p) * 2 + 1];
        rko[base] = v1 * cc - v2 * ss; rko[base + 1] = v1 * ss + v2 * cc;
      } else {
        vo[base] = v1; vo[base + 1] = v2;
      }
    }
  }
}

// gates = sigmoid(hn @ Wg), one thread per (token, j)
__global__ __launch_bounds__(256) void d_gates(const float* __restrict__ hn,
                                               const float* __restrict__ Wg,
                                               float* __restrict__ gates) {
  int gid = blockIdx.x * 256 + threadIdx.x;  // 196608
  int tok = gid / 24, j = gid % 24;
  const float* hr = hn + (size_t)tok * 256;
  float s = 0.f;
  for (int d = 0; d < 256; ++d) s += hr[d] * Wg[d * 24 + j];
  gates[gid] = 1.f / (1.f + expf(-s));
}

// gMLP layer 1: 64x64 tile, XCD-aware remap (8 m-tiles of one (n,h) panel share
// an XCD's L2), transposed As + float2/float4 LDS reads. K ascending => bit-exact.
__global__ __launch_bounds__(256) void k_gmlp1(const float* __restrict__ kv,
                                               const float* __restrict__ posw,
                                               const float* __restrict__ w1,
                                               float* __restrict__ hb) {
  __shared__ float As[32][66];
  __shared__ __align__(16) float Bs[32][68];
  // flat grid 1024: xcd = bid%8; within an XCD, consecutive work walks m fastest
  const int bid = blockIdx.x;
  const int xcd = bid & 7;
  const int idx = bid >> 3;            // 0..127
  const int mt  = idx & 7;             // m-tile
  const int nh  = xcd * 16 + (idx >> 3);  // 0..127
  const int n0 = (nh & 15) * 64;
  const int h  = nh >> 4;
  const int m0 = mt * 64;
  const int tid = threadIdx.x;
  const int tx = tid & 15, ty = tid >> 4;
  float acc[4][4] = {};
  for (int k0 = 0; k0 < 1024; k0 += 32) {
#pragma unroll
    for (int i = 0; i < 8; ++i) {
      int li = tid + i * 256;
      int mm = li >> 5, c = li & 31;
      int row = m0 + mm;
      float vv = 0.f;
      if (row < 496) {
        int nb = row / 31, bb = row % 31;
        vv = kv[((size_t)(nb * 8 + h) * 512 + bb * 16) * 32 + k0 + c] + posw[h * 1024 + k0 + c];
      }
      As[c][mm] = vv;
    }
#pragma unroll
    for (int i = 0; i < 8; ++i) {
      int li = tid + i * 256;
      int r = li >> 6, c = li & 63;
      Bs[r][c] = w1[(size_t)h * 1048576 + (size_t)(k0 + r) * 1024 + n0 + c];
    }
    __syncthreads();
#pragma unroll
    for (int kk = 0; kk < 32; ++kk) {
      float2 a0 = *reinterpret_cast<const float2*>(&As[kk][ty * 4]);
      float2 a1 = *reinterpret_cast<const float2*>(&As[kk][ty * 4 + 2]);
      float4 b4 = *reinterpret_cast<const float4*>(&Bs[kk][tx * 4]);
      float a[4] = {a0.x, a0.y, a1.x, a1.y};
      float b[4] = {b4.x, b4.y, b4.z, b4.w};
#pragma unroll
      for (int i = 0; i < 4; ++i)
#pragma unroll
        for (int j = 0; j < 4; ++j) acc[i][j] += a[i] * b[j];
    }
    __syncthreads();
  }
#pragma unroll
  for (int i = 0; i < 4; ++i) {
    int row = m0 + ty * 4 + i;
    if (row < 496) {
#pragma unroll
      for (int j = 0; j < 4; ++j)
        hb[((size_t)h * 496 + row) * 1024 + n0 + tx * 4 + j] = fmaxf(acc[i][j], 0.f);
    }
  }
}

// gMLP out: one thread per output, exact sequential i order (sel-sensitive)
__global__ __launch_bounds__(256) void d_g2(const float* __restrict__ hh,
                                            const float* __restrict__ w2,
                                            float* __restrict__ outp) {
  int gid = blockIdx.x * 256 + threadIdx.x;  // 126976
  int o = gid & 31;
  int rem = gid >> 5;                  // h*496 + row
  int h = rem / 496, row = rem % 496;
  int nb = row / 31, bb = row % 31;
  const float* hr = hh + (size_t)rem * 1024;
  const float* w2p = w2 + (size_t)h * 32768 + o;
  float s = 0.f;
  for (int i = 0; i < 1024; ++i) s += hr[i] * w2p[(size_t)i * 32];
  outp[((size_t)(nb * 8 + h) * 31 + bb) * 32 + o] = s;
}

// compressed attention, one thread per (nh, t): obuf = g0*c_out, emits sel
// (UNCHANGED: sel-sensitive)
__global__ __launch_bounds__(256) void d_cattn(const float* __restrict__ q,
                                               const float* __restrict__ ck,
                                               const float* __restrict__ cv,
                                               const float* __restrict__ mem_ck,
                                               const float* __restrict__ mem_cv,
                                               const float* __restrict__ gates,
                                               float* __restrict__ obuf,
                                               int* __restrict__ sel) {
  int gid = blockIdx.x * 256 + threadIdx.x;  // 65536
  int nh = gid >> 9, t = gid & 511;
  int h = nh & 7, ball = nh >> 3;
  const float* qp = q + (size_t)gid * 32;
  float sc[32];
  float mx = -INFINITY;
#pragma unroll
  for (int j = 0; j < 32; ++j) {
    float s = -INFINITY;
    bool valid = (j == 0) || (t >= (j - 1) * 16 + 31);
    if (valid) {
      const float* kp = (j == 0) ? (mem_ck + h * 32)
                                 : (ck + ((size_t)nh * 31 + (j - 1)) * 32);
      s = 0.f;
      for (int d = 0; d < 32; ++d) s += qp[d] * kp[d];
      s *= SCALE_;
    }
    sc[j] = s;
    mx = fmaxf(mx, s);
  }
  float e[32];
  float den = 0.f;
#pragma unroll
  for (int j = 0; j < 32; ++j) { e[j] = expf(sc[j] - mx); den += e[j]; }
  float num[32];
#pragma unroll
  for (int d = 0; d < 32; ++d) num[d] = 0.f;
#pragma unroll
  for (int j = 0; j < 32; ++j) {
    const float* vp = (j == 0) ? (mem_cv + h * 32)
                               : (cv + ((size_t)nh * 31 + (j - 1)) * 32);
    float p = e[j];
    for (int d = 0; d < 32; ++d) num[d] += p * vp[d];
  }
  float inv = 1.f / den;
  float g0 = gates[(size_t)(ball * 512 + t) * 24 + h * 3];
  float* op = obuf + (size_t)(ball * 512 + t) * 256 + h * 32;
  for (int d = 0; d < 32; ++d) op[d] = num[d] * inv * g0;

  int s_idx = 0;
  if (t >= 32) {
    int fn = t >> 5;
    float best = -INFINITY;
    for (int f = 0; f < fn; ++f) {
      float im = 0.f;
#pragma unroll
      for (int j = 0; j < 31; ++j) {
        int a = j * 16, b2 = a + 32, fa = f * 32, fb = fa + 32;
        int lo = a > fa ? a : fa;
        int hi = b2 < fb ? b2 : fb;
        if (hi > lo) im += e[j + 1] * (float)(hi - lo) * (1.f / 32.f);
      }
      if (im > best) { best = im; s_idx = f; }
    }
  }
  sel[gid] = s_idx;
}

// fine attention: block per (f0,h,nb), LDS-staged own tile, 8 lanes/query.
__global__ __launch_bounds__(256) void k_fattn(const float* __restrict__ rq,
                                               const float* __restrict__ rk,
                                               const float* __restrict__ v,
                                               const int* __restrict__ sel,
                                               const float* __restrict__ gates,
                                               float* __restrict__ obuf) {
  int f0 = blockIdx.x, h = blockIdx.y, nb = blockIdx.z;
  int nh = nb * 8 + h;
  __shared__ float rqs[32][33], rks[32][33], vs[32][33];
  for (int i = threadIdx.x; i < 1024; i += 256) {
    int r = i >> 5, d = i & 31;
    size_t base = ((size_t)nh * 512 + f0 * 32 + r) * 32 + d;
    rqs[r][d] = rq[base];
    rks[r][d] = rk[base];
    vs[r][d]  = v[base];
  }
  __syncthreads();
  int qi = threadIdx.x >> 3, l = threadIdx.x & 7;
  int t = f0 * 32 + qi;
  int sb = sel[(size_t)nh * 512 + t];
  bool hs = (t >= 32);
  float p[8];
  float mx = -INFINITY;
#pragma unroll
  for (int kk2 = 0; kk2 < 8; ++kk2) {
    int kk = l * 8 + kk2;
    float s = -INFINITY;
    if (kk < 32) {
      if (qi >= kk) {
        s = 0.f;
#pragma unroll
        for (int d = 0; d < 32; ++d) s += rqs[qi][d] * rks[kk][d];
        s *= SCALE_;
      }
    } else if (hs) {
      const float* kp = rk + ((size_t)nh * 512 + sb * 32 + (kk - 32)) * 32;
      s = 0.f;
#pragma unroll
      for (int d = 0; d < 32; ++d) s += rqs[qi][d] * kp[d];
      s *= SCALE_;
    }
    p[kk2] = s;
    mx = fmaxf(mx, s);
  }
#pragma unroll
  for (int off = 4; off; off >>= 1) mx = fmaxf(mx, __shfl_xor(mx, off, 8));
  float sum = 0.f;
#pragma unroll
  for (int kk2 = 0; kk2 < 8; ++kk2) { p[kk2] = expf(p[kk2] - mx); sum += p[kk2]; }
#pragma unroll
  for (int off = 4; off; off >>= 1) sum += __shfl_xor(sum, off, 8);
  float inv = 1.f / sum;
  float acc[32];
#pragma unroll
  for (int d = 0; d < 32; ++d) acc[d] = 0.f;
#pragma unroll
  for (int kk2 = 0; kk2 < 8; ++kk2) {
    int kk = l * 8 + kk2;
    float pw = p[kk2] * inv;
    if (kk < 32) {
#pragma unroll
      for (int d = 0; d < 32; ++d) acc[d] += pw * vs[kk][d];
    } else if (hs) {
      const float* vp = v + ((size_t)nh * 512 + sb * 32 + (kk - 32)) * 32;
#pragma unroll
      for (int d = 0; d < 32; ++d) acc[d] += pw * vp[d];
    }
  }
#pragma unroll
  for (int off = 4; off; off >>= 1) {
#pragma unroll
    for (int d = 0; d < 32; ++d) acc[d] += __shfl_xor(acc[d], off, 8);
  }
  float g1 = gates[(size_t)(nb * 512 + t) * 24 + h * 3 + 1];
  float* op = obuf + (size_t)(nb * 512 + t) * 256 + h * 32;
#pragma unroll
  for (int j = 0; j < 4; ++j) op[l * 4 + j] += acc[l * 4 + j] * g1;
}

// sliding-window attention: block per (b,h,nb), LDS-staged 64-key window.
__global__ __launch_bounds__(256) void k_swattn(const float* __restrict__ rq,
                                                const float* __restrict__ rk,
                                                const float* __restrict__ v,
                                                const float* __restrict__ gates,
                                                float* __restrict__ obuf) {
  int b = blockIdx.x, h = blockIdx.y, nb = blockIdx.z;
  int nh = nb * 8 + h;
  __shared__ float rqs[32][33], k2s[64][33], v2s[64][33];
  for (int i = threadIdx.x; i < 1024; i += 256) {
    int r = i >> 5, d = i & 31;
    rqs[r][d] = rq[((size_t)nh * 512 + b * 32 + r) * 32 + d];
  }
  for (int i = threadIdx.x; i < 2048; i += 256) {
    int r = i >> 5, d = i & 31;
    int tk = (b - 1) * 32 + r;
    float kk_ = 0.f, vv_ = 0.f;
    if (tk >= 0) {
      kk_ = rk[((size_t)nh * 512 + tk) * 32 + d];
      vv_ = v[((size_t)nh * 512 + tk) * 32 + d];
    }
    k2s[r][d] = kk_;
    v2s[r][d] = vv_;
  }
  __syncthreads();
  int qi = threadIdx.x >> 3, l = threadIdx.x & 7;
  int t = b * 32 + qi;
  float p[8];
  float mx = -INFINITY;
#pragma unroll
  for (int kk2 = 0; kk2 < 8; ++kk2) {
    int kk = l * 8 + kk2;
    bool valid = (kk > qi) && (kk <= qi + 32) && ((b > 0) || (kk >= 32));
    float s = -INFINITY;
    if (valid) {
      s = 0.f;
#pragma unroll
      for (int d = 0; d < 32; ++d) s += rqs[qi][d] * k2s[kk][d];
      s *= SCALE_;
    }
    p[kk2] = s;
    mx = fmaxf(mx, s);
  }
#pragma unroll
  for (int off = 4; off; off >>= 1) mx = fmaxf(mx, __shfl_xor(mx, off, 8));
  float sum = 0.f;
#pragma unroll
  for (int kk2 = 0; kk2 < 8; ++kk2) { p[kk2] = expf(p[kk2] - mx); sum += p[kk2]; }
#pragma unroll
  for (int off = 4; off; off >>= 1) sum += __shfl_xor(sum, off, 8);
  float inv = 1.f / sum;
  float acc[32];
#pragma unroll
  for (int d = 0; d < 32; ++d) acc[d] = 0.f;
#pragma unroll
  for (int kk2 = 0; kk2 < 8; ++kk2) {
    int kk = l * 8 + kk2;
    float pw = p[kk2] * inv;  // invalid entries have p=0
#pragma unroll
    for (int d = 0; d < 32; ++d) acc[d] += pw * v2s[kk][d];
  }
#pragma unroll
  for (int off = 4; off; off >>= 1) {
#pragma unroll
    for (int d = 0; d < 32; ++d) acc[d] += __shfl_xor(acc[d], off, 8);
  }
  float g2 = gates[(size_t)(nb * 512 + t) * 24 + h * 3 + 2];
  float* op = obuf + (size_t)(nb * 512 + t) * 256 + h * 32;
#pragma unroll
  for (int j = 0; j < 4; ++j) op[l * 4 + j] += acc[l * 4 + j] * g2;
}

// final projection tiled: out = obuf @ Wo (f32 store); transposed As scheme
__global__ __launch_bounds__(256) void k_out(const float* __restrict__ A,
                                             const float* __restrict__ B,
                                             float* __restrict__ C) {
  __shared__ float As[32][66];
  __shared__ __align__(16) float Bs[32][68];
  const int m0 = blockIdx.x * 64;
  const int n0 = blockIdx.y * 64;
  const int tid = threadIdx.x;
  const int tx = tid & 15, ty = tid >> 4;
  float acc[4][4] = {};
  for (int k0 = 0; k0 < 256; k0 += 32) {
#pragma unroll
    for (int i = 0; i < 8; ++i) {
      int li = tid + i * 256;
      int mm = li >> 5, c = li & 31;
      As[c][mm] = A[(size_t)(m0 + mm) * 256 + k0 + c];
    }
#pragma unroll
    for (int i = 0; i < 8; ++i) {
      int li = tid + i * 256;
      int r = li >> 6, c = li & 63;
      Bs[r][c] = B[(size_t)(k0 + r) * 256 + n0 + c];
    }
    __syncthreads();
#pragma unroll
    for (int kk = 0; kk < 32; ++kk) {
      float2 a0 = *reinterpret_cast<const float2*>(&As[kk][ty * 4]);
      float2 a1 = *reinterpret_cast<const float2*>(&As[kk][ty * 4 + 2]);
      float4 b4 = *reinterpret_cast<const float4*>(&Bs[kk][tx * 4]);
      float a[4] = {a0.x, a0.y, a1.x, a1.y};
      float b[4] = {b4.x, b4.y, b4.z, b4.w};
#pragma unroll
      for (int i = 0; i < 4; ++i)
#pragma unroll
        for (int j = 0; j < 4; ++j) acc[i][j] += a[i] * b[j];
    }
    __syncthreads();
  }
#pragma unroll
  for (int i = 0; i < 4; ++i) {
    int row = m0 + ty * 4 + i;
#pragma unroll
    for (int j = 0; j < 4; ++j)
      C[(size_t)row * 256 + n0 + tx * 4 + j] = acc[i][j];
  }
}

extern "C" void kernel_launch(void* const* d_in, const int* in_sizes, int n_in,
                              void* d_out, int out_size, void* d_ws, size_t ws_size,
                              hipStream_t stream) {
  const float* x      = (const float*)d_in[0];
  const float* pos    = (const float*)d_in[1];
  const float* Wpe    = (const float*)d_in[2];
  const float* bpe    = (const float*)d_in[3];
  const float* rms_w  = (const float*)d_in[4];
  const float* Wqkv   = (const float*)d_in[5];
  const float* kpos   = (const float*)d_in[6];
  const float* vpos   = (const float*)d_in[7];
  const float* kw1    = (const float*)d_in[8];
  const float* kw2    = (const float*)d_in[9];
  const float* vw1    = (const float*)d_in[10];
  const float* vw2    = (const float*)d_in[11];
  const float* mem_ck = (const float*)d_in[12];
  const float* mem_cv = (const float*)d_in[13];
  const float* Wg     = (const float*)d_in[14];
  const float* Wo     = (const float*)d_in[15];
  float* out = (float*)d_out;

  float* ws = (float*)d_ws;
  const size_t TOK = 2097152;  // 8192*256
  float* hn    = ws;
  float* q     = ws + TOK;
  float* k     = ws + 2 * TOK;
  float* v     = ws + 3 * TOK;
  float* rq    = ws + 4 * TOK;
  float* rk    = ws + 5 * TOK;
  float* obuf  = ws + 6 * TOK;
  float* hh    = ws + 7 * TOK;       // 4,063,232
  float* ck    = hh + 4063232;
  float* cv    = ck + 126976;
  float* gates = cv + 126976;
  float* rope  = gates + 196608;
  float* pm    = rope + 16384;
  int*   sel   = (int*)(pm + 64);

  d_rope<<<32, 256, 0, stream>>>(rope);
  k_pm<<<16, 256, 0, stream>>>(pos, pm);
  k_hn<<<256, 256, 0, stream>>>(x, pos, pm, Wpe, bpe, rms_w, hn);
  k_qkv<<<dim3(128, 12), 256, 0, stream>>>(hn, Wqkv, rope, q, k, v, rq, rk);
  d_gates<<<768, 256, 0, stream>>>(hn, Wg, gates);
  k_gmlp1<<<1024, 256, 0, stream>>>(k, kpos, kw1, hh);
  d_g2<<<496, 256, 0, stream>>>(hh, kw2, ck);
  k_gmlp1<<<1024, 256, 0, stream>>>(v, vpos, vw1, hh);
  d_g2<<<496, 256, 0, stream>>>(hh, vw2, cv);
  d_cattn<<<256, 256, 0, stream>>>(q, ck, cv, mem_ck, mem_cv, gates, obuf, sel);
  k_fattn<<<dim3(16, 8, 16), 256, 0, stream>>>(rq, rk, v, sel, gates, obuf);
  k_swattn<<<dim3(16, 8, 16), 256, 0, stream>>>(rq, rk, v, gates, obuf);
  k_out<<<dim3(128, 4), 256, 0, stream>>>(obuf, Wo, out);
}